// Round 1
// baseline (717.926 us; speedup 1.0000x reference)
//
#include <hip/hip_runtime.h>
#include <hip/hip_bf16.h>

// Problem constants (match reference)
constexpr int N   = 50000;     // nodes
constexpr int R   = 51;        // relations
constexpr int E   = 16;        // emb dim
constexpr int C   = 8;         // classes
constexpr int B   = 40;        // bases
constexpr int NNZ = 1600000;   // edges

// ---------------------------------------------------------------------------
// K1: W1 = comps1(R,B) @ bases1(B, N*E)  -> W1 (R, N*E) row-major
//     (identical memory to (R*N, E) row-major: 64B per gather row)
// Each thread owns one float2 column; bases column kept in registers.
// ---------------------------------------------------------------------------
__global__ __launch_bounds__(256) void w1_gemm_kernel(
    const float* __restrict__ comps1, const float* __restrict__ bases1,
    float* __restrict__ W1) {
  constexpr int NC2 = N * E / 2;  // 400000 float2 columns
  int j = blockIdx.x * blockDim.x + threadIdx.x;
  if (j >= NC2) return;
  const float2* b2 = reinterpret_cast<const float2*>(bases1);
  float2 col[B];
#pragma unroll
  for (int b = 0; b < B; ++b) col[b] = b2[b * NC2 + j];
  float2* w2p = reinterpret_cast<float2*>(W1);
#pragma unroll 1
  for (int r = 0; r < R; ++r) {
    float ax = 0.f, ay = 0.f;
#pragma unroll
    for (int b = 0; b < B; ++b) {
      float cc = comps1[r * B + b];   // uniform -> scalar loads
      ax = fmaf(cc, col[b].x, ax);
      ay = fmaf(cc, col[b].y, ay);
    }
    w2p[r * NC2 + j] = make_float2(ax, ay);
  }
}

// ---------------------------------------------------------------------------
// K2: histogram of hor_rows (s)
// ---------------------------------------------------------------------------
__global__ void hist_kernel(const int* __restrict__ rows,
                            int* __restrict__ counts) {
  int stride = gridDim.x * blockDim.x;
  for (int i = blockIdx.x * blockDim.x + threadIdx.x; i < NNZ; i += stride)
    atomicAdd(&counts[rows[i]], 1);
}

// ---------------------------------------------------------------------------
// K3: exclusive scan of counts -> offs[N+1], cursor[N] (single block)
// ---------------------------------------------------------------------------
constexpr int SCAN_T = 1024;
__global__ __launch_bounds__(SCAN_T) void scan_kernel(
    const int* __restrict__ counts, int* __restrict__ offs,
    int* __restrict__ cursor) {
  __shared__ int lsum[SCAN_T];
  int t = threadIdx.x;
  constexpr int CH = (N + SCAN_T - 1) / SCAN_T;  // 49
  int lo = t * CH;
  int hi = lo + CH < N ? lo + CH : N;
  int s = 0;
  for (int i = lo; i < hi; ++i) s += counts[i];
  lsum[t] = s;
  __syncthreads();
  for (int d = 1; d < SCAN_T; d <<= 1) {   // inclusive Hillis-Steele
    int v = (t >= d) ? lsum[t - d] : 0;
    __syncthreads();
    lsum[t] += v;
    __syncthreads();
  }
  int run = (t > 0) ? lsum[t - 1] : 0;     // exclusive base
  for (int i = lo; i < hi; ++i) {
    offs[i] = run;
    cursor[i] = run;
    run += counts[i];
  }
  if (t == SCAN_T - 1) offs[N] = lsum[SCAN_T - 1];  // = NNZ
}

// ---------------------------------------------------------------------------
// K4: scatter edges into s-sorted order: scols[pos]=p*N+o, svals[pos]=v
// ---------------------------------------------------------------------------
__global__ void scatter_kernel(const int* __restrict__ rows,
                               const int* __restrict__ cols,
                               const float* __restrict__ vals,
                               int* __restrict__ cursor,
                               int* __restrict__ scols,
                               float* __restrict__ svals) {
  int stride = gridDim.x * blockDim.x;
  for (int i = blockIdx.x * blockDim.x + threadIdx.x; i < NNZ; i += stride) {
    int r = rows[i];
    int pos = atomicAdd(&cursor[r], 1);
    scols[pos] = cols[i];
    svals[pos] = vals[i];
  }
}

// ---------------------------------------------------------------------------
// K5: W2 = comps2(R,B) @ bases2(B, E*C)  -> W2g (R, E*C)  (tiny)
// ---------------------------------------------------------------------------
__global__ void w2_gemm_kernel(const float* __restrict__ comps2,
                               const float* __restrict__ bases2,
                               float* __restrict__ W2g) {
  int i = blockIdx.x * blockDim.x + threadIdx.x;
  if (i >= R * E * C) return;
  int r = i >> 7;        // / (E*C)
  int ec = i & 127;
  float acc = 0.f;
#pragma unroll
  for (int b = 0; b < B; ++b) acc = fmaf(comps2[r * B + b], bases2[b * 128 + ec], acc);
  W2g[i] = acc;
}

// ---------------------------------------------------------------------------
// K6: layer 1 — per node s: h[s] = relu(bias1 + sum_edges v * W1[p*N+o, :])
// One wave per node; 4 lanes per edge (float4 each) -> 16 edges in flight.
// ---------------------------------------------------------------------------
__global__ __launch_bounds__(256) void layer1_kernel(
    const float* __restrict__ W1, const int* __restrict__ offs,
    const int* __restrict__ scols, const float* __restrict__ svals,
    const float* __restrict__ bias1, float* __restrict__ h) {
  int node = (blockIdx.x * blockDim.x + threadIdx.x) >> 6;
  if (node >= N) return;
  int lane = threadIdx.x & 63;
  int g = lane >> 2;    // edge slot 0..15
  int sub = lane & 3;   // float4 piece
  int start = offs[node], end = offs[node + 1];
  float4 acc = make_float4(0.f, 0.f, 0.f, 0.f);
  const float4* W14 = reinterpret_cast<const float4*>(W1);
  for (int e = start + g; e < end; e += 16) {
    int cidx = scols[e];
    float v = svals[e];
    float4 w = W14[cidx * 4 + sub];
    acc.x = fmaf(v, w.x, acc.x);
    acc.y = fmaf(v, w.y, acc.y);
    acc.z = fmaf(v, w.z, acc.z);
    acc.w = fmaf(v, w.w, acc.w);
  }
#pragma unroll
  for (int m = 4; m <= 32; m <<= 1) {
    acc.x += __shfl_xor(acc.x, m);
    acc.y += __shfl_xor(acc.y, m);
    acc.z += __shfl_xor(acc.z, m);
    acc.w += __shfl_xor(acc.w, m);
  }
  if (g == 0) {
    float4 bb = reinterpret_cast<const float4*>(bias1)[sub];
    float4 r;
    r.x = fmaxf(acc.x + bb.x, 0.f);
    r.y = fmaxf(acc.y + bb.y, 0.f);
    r.z = fmaxf(acc.z + bb.z, 0.f);
    r.w = fmaxf(acc.w + bb.w, 0.f);
    reinterpret_cast<float4*>(h)[node * 4 + sub] = r;
  }
}

// ---------------------------------------------------------------------------
// K7: layer 2 fused — out[s,c] = bias2[c] + sum_edges v * (h[o,:] . W2[p,:,c])
// One wave per node; 8 lanes per edge (lane = class c) -> 8 edges in flight.
// W2 staged in LDS with stride 129 (bank spread across relations).
// ---------------------------------------------------------------------------
__global__ __launch_bounds__(256) void layer2_kernel(
    const float* __restrict__ h, const float* __restrict__ W2g,
    const int* __restrict__ offs, const int* __restrict__ scols,
    const float* __restrict__ svals, const float* __restrict__ bias2,
    float* __restrict__ out) {
  __shared__ float w2s[R * 129];
  for (int i = threadIdx.x; i < R * E * C; i += blockDim.x) {
    int p = i >> 7, ec = i & 127;
    w2s[p * 129 + ec] = W2g[i];
  }
  __syncthreads();
  int node = (blockIdx.x * blockDim.x + threadIdx.x) >> 6;
  if (node >= N) return;
  int lane = threadIdx.x & 63;
  int g = lane >> 3;   // edge slot 0..7
  int c = lane & 7;    // class
  int start = offs[node], end = offs[node + 1];
  float acc = 0.f;
  const float4* H4 = reinterpret_cast<const float4*>(h);
  for (int e = start + g; e < end; e += 8) {
    int col = scols[e];
    float v = svals[e];
    int p = (int)((unsigned)col / (unsigned)N);   // magic-mul
    int o = col - p * N;
    float4 h0 = H4[o * 4 + 0];
    float4 h1 = H4[o * 4 + 1];
    float4 h2 = H4[o * 4 + 2];
    float4 h3 = H4[o * 4 + 3];
    const float* wp = &w2s[p * 129 + c];
    float s;
    s  = h0.x * wp[0]   + h0.y * wp[8]   + h0.z * wp[16]  + h0.w * wp[24];
    s += h1.x * wp[32]  + h1.y * wp[40]  + h1.z * wp[48]  + h1.w * wp[56];
    s += h2.x * wp[64]  + h2.y * wp[72]  + h2.z * wp[80]  + h2.w * wp[88];
    s += h3.x * wp[96]  + h3.y * wp[104] + h3.z * wp[112] + h3.w * wp[120];
    acc = fmaf(v, s, acc);
  }
#pragma unroll
  for (int m = 8; m <= 32; m <<= 1) acc += __shfl_xor(acc, m);
  if (g == 0) out[node * 8 + c] = acc + bias2[c];
}

// ---------------------------------------------------------------------------
extern "C" void kernel_launch(void* const* d_in, const int* in_sizes, int n_in,
                              void* d_out, int out_size, void* d_ws, size_t ws_size,
                              hipStream_t stream) {
  const float* values  = (const float*)d_in[0];
  const float* comps1  = (const float*)d_in[1];
  const float* bases1  = (const float*)d_in[2];
  const float* comps2  = (const float*)d_in[3];
  const float* bases2  = (const float*)d_in[4];
  const float* bias1   = (const float*)d_in[5];
  const float* bias2   = (const float*)d_in[6];
  const int* hor_rows  = (const int*)d_in[7];
  const int* hor_cols  = (const int*)d_in[8];
  // ver_rows / ver_cols (d_in[9], d_in[10]) not needed: derivable from hor.
  float* out = (float*)d_out;

  char* ws = (char*)d_ws;
  size_t off = 0;
  auto alloc = [&](size_t bytes) {
    void* p = ws + off;
    off += (bytes + 255) & ~size_t(255);
    return p;
  };
  float* W1    = (float*)alloc((size_t)R * N * E * 4);  // 163.2 MB
  float* h     = (float*)alloc((size_t)N * E * 4);      // 3.2 MB
  float* W2g   = (float*)alloc((size_t)R * E * C * 4);  // 26 KB
  int*   offs  = (int*)alloc((size_t)(N + 1) * 4);
  int*   cursor= (int*)alloc((size_t)N * 4);
  int*   counts= (int*)alloc((size_t)N * 4);
  int*   scols = (int*)alloc((size_t)NNZ * 4);          // 6.4 MB
  float* svals = (float*)alloc((size_t)NNZ * 4);        // 6.4 MB
  (void)ws_size; (void)in_sizes; (void)n_in; (void)out_size;

  hipMemsetAsync(counts, 0, (size_t)N * 4, stream);

  w1_gemm_kernel<<<(N * E / 2 + 255) / 256, 256, 0, stream>>>(comps1, bases1, W1);
  hist_kernel<<<1024, 256, 0, stream>>>(hor_rows, counts);
  scan_kernel<<<1, SCAN_T, 0, stream>>>(counts, offs, cursor);
  scatter_kernel<<<1024, 256, 0, stream>>>(hor_rows, hor_cols, values, cursor,
                                           scols, svals);
  w2_gemm_kernel<<<(R * E * C + 255) / 256, 256, 0, stream>>>(comps2, bases2, W2g);
  layer1_kernel<<<(N * 64) / 256, 256, 0, stream>>>(W1, offs, scols, svals,
                                                    bias1, h);
  layer2_kernel<<<(N * 64) / 256, 256, 0, stream>>>(h, W2g, offs, scols, svals,
                                                    bias2, out);
}

// Round 2
// 621.989 us; speedup vs baseline: 1.1542x; 1.1542x over previous
//
#include <hip/hip_runtime.h>
#include <hip/hip_bf16.h>

// Problem constants (match reference)
constexpr int N   = 50000;     // nodes
constexpr int R   = 51;        // relations
constexpr int E   = 16;        // emb dim
constexpr int C   = 8;         // classes
constexpr int B   = 40;        // bases
constexpr int NNZ = 1600000;   // edges

// Bucketed counting sort: 64 nodes per bucket -> LDS-resident accumulators
constexpr int BSH   = 6;                     // log2(nodes per bucket)
constexpr int BKN   = 1 << BSH;              // 64 nodes / bucket
constexpr int NB    = (N + BKN - 1) >> BSH;  // 782 buckets
constexpr int NBLK  = 784;                   // blocks for count/scatter passes
constexpr int CHUNK = (NNZ + NBLK - 1) / NBLK;  // 2041 edges / block

// ---------------------------------------------------------------------------
// K1: W1 = comps1(R,B) @ bases1(B, N*E) -> W1 (R, N*E) row-major
//     == (R*N, E) row-major: one 64B contiguous row per gather target.
// ---------------------------------------------------------------------------
__global__ __launch_bounds__(256) void w1_gemm_kernel(
    const float* __restrict__ comps1, const float* __restrict__ bases1,
    float* __restrict__ W1) {
  constexpr int NC2 = N * E / 2;  // 400000 float2 columns
  int j = blockIdx.x * blockDim.x + threadIdx.x;
  if (j >= NC2) return;
  const float2* b2 = reinterpret_cast<const float2*>(bases1);
  float2 col[B];
#pragma unroll
  for (int b = 0; b < B; ++b) col[b] = b2[b * NC2 + j];
  float2* w2p = reinterpret_cast<float2*>(W1);
#pragma unroll 1
  for (int r = 0; r < R; ++r) {
    float ax = 0.f, ay = 0.f;
#pragma unroll
    for (int b = 0; b < B; ++b) {
      float cc = comps1[r * B + b];   // block-uniform -> scalar loads
      ax = fmaf(cc, col[b].x, ax);
      ay = fmaf(cc, col[b].y, ay);
    }
    w2p[r * NC2 + j] = make_float2(ax, ay);
  }
}

// ---------------------------------------------------------------------------
// K2: bucket histogram (LDS-aggregated; ~150k global atomics total)
// ---------------------------------------------------------------------------
__global__ __launch_bounds__(256) void count_kernel(
    const int* __restrict__ rows, int* __restrict__ gcount) {
  __shared__ int hist[NB];
  for (int i = threadIdx.x; i < NB; i += 256) hist[i] = 0;
  __syncthreads();
  int lo = blockIdx.x * CHUNK;
  int hi = lo + CHUNK < NNZ ? lo + CHUNK : NNZ;
  for (int i = lo + threadIdx.x; i < hi; i += 256)
    atomicAdd(&hist[rows[i] >> BSH], 1);
  __syncthreads();
  for (int i = threadIdx.x; i < NB; i += 256)
    if (hist[i]) atomicAdd(&gcount[i], hist[i]);
}

// ---------------------------------------------------------------------------
// K3: scan of 782 bucket counts -> gstart[NB+1], gcursor[NB]
// ---------------------------------------------------------------------------
__global__ __launch_bounds__(1024) void scan_kernel(
    const int* __restrict__ gcount, int* __restrict__ gstart,
    int* __restrict__ gcursor) {
  __shared__ int buf[1024];
  int t = threadIdx.x;
  int own = (t < NB) ? gcount[t] : 0;
  buf[t] = own;
  __syncthreads();
  for (int d = 1; d < 1024; d <<= 1) {  // inclusive Hillis-Steele
    int v = (t >= d) ? buf[t - d] : 0;
    __syncthreads();
    buf[t] += v;
    __syncthreads();
  }
  if (t < NB) {
    int st = buf[t] - own;  // exclusive
    gstart[t] = st;
    gcursor[t] = st;
  }
  if (t == NB - 1) gstart[NB] = buf[t];  // = NNZ
}

// ---------------------------------------------------------------------------
// K4: scatter edges into bucket-grouped order, packed 8B records:
//     word0 = (s_lo << 26) | col   (col = p*N+o < 2^22),  word1 = val bits
//     Block-aggregated cursors -> multi-edge runs per bucket (burst writes).
// ---------------------------------------------------------------------------
__global__ __launch_bounds__(256) void scatter_kernel(
    const int* __restrict__ rows, const int* __restrict__ cols,
    const float* __restrict__ vals, int* __restrict__ gcursor,
    int2* __restrict__ packed) {
  __shared__ int hist[NB];
  __shared__ int base[NB];
  for (int i = threadIdx.x; i < NB; i += 256) hist[i] = 0;
  __syncthreads();
  int lo = blockIdx.x * CHUNK;
  int hi = lo + CHUNK < NNZ ? lo + CHUNK : NNZ;
  for (int i = lo + threadIdx.x; i < hi; i += 256)
    atomicAdd(&hist[rows[i] >> BSH], 1);
  __syncthreads();
  for (int i = threadIdx.x; i < NB; i += 256) {
    int c = hist[i];
    base[i] = c ? atomicAdd(&gcursor[i], c) : 0;
  }
  __syncthreads();
  for (int i = threadIdx.x; i < NB; i += 256) hist[i] = 0;  // reuse as cursor
  __syncthreads();
  for (int i = lo + threadIdx.x; i < hi; i += 256) {
    int s = rows[i];
    int b = s >> BSH;
    int pos = base[b] + atomicAdd(&hist[b], 1);
    packed[pos] = make_int2(((s & (BKN - 1)) << 26) | cols[i],
                            __float_as_int(vals[i]));
  }
}

// ---------------------------------------------------------------------------
// K5: W2 = comps2(R,B) @ bases2(B, E*C)  (tiny)
// ---------------------------------------------------------------------------
__global__ void w2_gemm_kernel(const float* __restrict__ comps2,
                               const float* __restrict__ bases2,
                               float* __restrict__ W2g) {
  int i = blockIdx.x * blockDim.x + threadIdx.x;
  if (i >= R * E * C) return;
  int r = i >> 7;
  int ec = i & 127;
  float acc = 0.f;
#pragma unroll
  for (int b = 0; b < B; ++b)
    acc = fmaf(comps2[r * B + b], bases2[b * 128 + ec], acc);
  W2g[i] = acc;
}

// ---------------------------------------------------------------------------
// K6: layer 1 — one block per bucket, LDS fp32 accumulators (stride 17).
//     Per edge: 64B W1 row gather + 16 ds_add_f32.
// ---------------------------------------------------------------------------
__global__ __launch_bounds__(256) void layer1_kernel(
    const float* __restrict__ W1, const int* __restrict__ gstart,
    const int2* __restrict__ packed, const float* __restrict__ bias1,
    float* __restrict__ h) {
  __shared__ float hacc[BKN * 17];
  for (int i = threadIdx.x; i < BKN * 17; i += 256) hacc[i] = 0.f;
  __syncthreads();
  int bkt = blockIdx.x;
  int lo = gstart[bkt], hi = gstart[bkt + 1];
  const float4* W14 = reinterpret_cast<const float4*>(W1);
  for (int e = lo + threadIdx.x; e < hi; e += 256) {
    int2 pk = packed[e];
    int slo = ((unsigned)pk.x) >> 26;
    int col = pk.x & ((1 << 26) - 1);
    float v = __int_as_float(pk.y);
    float4 w0 = W14[col * 4 + 0];
    float4 w1 = W14[col * 4 + 1];
    float4 w2 = W14[col * 4 + 2];
    float4 w3 = W14[col * 4 + 3];
    float* hp = &hacc[slo * 17];
    atomicAdd(hp + 0,  v * w0.x);
    atomicAdd(hp + 1,  v * w0.y);
    atomicAdd(hp + 2,  v * w0.z);
    atomicAdd(hp + 3,  v * w0.w);
    atomicAdd(hp + 4,  v * w1.x);
    atomicAdd(hp + 5,  v * w1.y);
    atomicAdd(hp + 6,  v * w1.z);
    atomicAdd(hp + 7,  v * w1.w);
    atomicAdd(hp + 8,  v * w2.x);
    atomicAdd(hp + 9,  v * w2.y);
    atomicAdd(hp + 10, v * w2.z);
    atomicAdd(hp + 11, v * w2.w);
    atomicAdd(hp + 12, v * w3.x);
    atomicAdd(hp + 13, v * w3.y);
    atomicAdd(hp + 14, v * w3.z);
    atomicAdd(hp + 15, v * w3.w);
  }
  __syncthreads();
  for (int i = threadIdx.x; i < BKN * E; i += 256) {
    int slo = i >> 4, e = i & 15;
    int node = (bkt << BSH) + slo;
    if (node < N)
      h[node * E + e] = fmaxf(hacc[slo * 17 + e] + bias1[e], 0.f);
  }
}

// ---------------------------------------------------------------------------
// K7: layer 2 — one block per bucket; W2 in LDS as [p][c][e] (stride 132,
//     16B-aligned rows -> ds_read_b128); LDS out accumulators (stride 9).
//     out[s,c] = bias2[c] + sum_edges v * (h[o,:] . W2[p,:,c])
// ---------------------------------------------------------------------------
__global__ __launch_bounds__(256) void layer2_kernel(
    const float* __restrict__ h, const float* __restrict__ W2g,
    const int* __restrict__ gstart, const int2* __restrict__ packed,
    const float* __restrict__ bias2, float* __restrict__ out) {
  __shared__ float w2s[R * 132];
  __shared__ float oacc[BKN * 9];
  for (int i = threadIdx.x; i < R * E * C; i += 256) {
    int p = i >> 7, ec = i & 127;     // W2g layout [p][e][c]
    int e = ec >> 3, c = ec & 7;
    w2s[p * 132 + c * 16 + e] = W2g[i];
  }
  for (int i = threadIdx.x; i < BKN * 9; i += 256) oacc[i] = 0.f;
  __syncthreads();
  int bkt = blockIdx.x;
  int lo = gstart[bkt], hi = gstart[bkt + 1];
  const float4* H4 = reinterpret_cast<const float4*>(h);
  for (int idx = lo + threadIdx.x; idx < hi; idx += 256) {
    int2 pk = packed[idx];
    int slo = ((unsigned)pk.x) >> 26;
    int col = pk.x & ((1 << 26) - 1);
    float v = __int_as_float(pk.y);
    int p = (int)((unsigned)col / (unsigned)N);
    int o = col - p * N;
    float4 h0 = H4[o * 4 + 0];
    float4 h1 = H4[o * 4 + 1];
    float4 h2 = H4[o * 4 + 2];
    float4 h3 = H4[o * 4 + 3];
    const float4* wp = reinterpret_cast<const float4*>(&w2s[p * 132]);
#pragma unroll
    for (int c = 0; c < 8; ++c) {
      float4 a = wp[c * 4 + 0];
      float4 bq = wp[c * 4 + 1];
      float4 cq = wp[c * 4 + 2];
      float4 dq = wp[c * 4 + 3];
      float s = h0.x * a.x + h0.y * a.y + h0.z * a.z + h0.w * a.w
              + h1.x * bq.x + h1.y * bq.y + h1.z * bq.z + h1.w * bq.w
              + h2.x * cq.x + h2.y * cq.y + h2.z * cq.z + h2.w * cq.w
              + h3.x * dq.x + h3.y * dq.y + h3.z * dq.z + h3.w * dq.w;
      atomicAdd(&oacc[slo * 9 + c], v * s);
    }
  }
  __syncthreads();
  for (int i = threadIdx.x; i < BKN * C; i += 256) {
    int slo = i >> 3, c = i & 7;
    int node = (bkt << BSH) + slo;
    if (node < N) out[node * C + c] = oacc[slo * 9 + c] + bias2[c];
  }
}

// ---------------------------------------------------------------------------
extern "C" void kernel_launch(void* const* d_in, const int* in_sizes, int n_in,
                              void* d_out, int out_size, void* d_ws, size_t ws_size,
                              hipStream_t stream) {
  const float* values  = (const float*)d_in[0];
  const float* comps1  = (const float*)d_in[1];
  const float* bases1  = (const float*)d_in[2];
  const float* comps2  = (const float*)d_in[3];
  const float* bases2  = (const float*)d_in[4];
  const float* bias1   = (const float*)d_in[5];
  const float* bias2   = (const float*)d_in[6];
  const int* hor_rows  = (const int*)d_in[7];
  const int* hor_cols  = (const int*)d_in[8];
  // ver_rows / ver_cols derivable from hor (ver_rows = p*N+s; same edges).
  float* out = (float*)d_out;

  char* ws = (char*)d_ws;
  size_t off = 0;
  auto alloc = [&](size_t bytes) {
    void* p = ws + off;
    off += (bytes + 255) & ~size_t(255);
    return p;
  };
  float* W1     = (float*)alloc((size_t)R * N * E * 4);   // 163.2 MB
  float* h      = (float*)alloc((size_t)N * E * 4);       // 3.2 MB
  float* W2g    = (float*)alloc((size_t)R * E * C * 4);   // 26 KB
  int*   gcount = (int*)alloc((size_t)NB * 4);
  int*   gstart = (int*)alloc((size_t)(NB + 1) * 4);
  int*   gcursor= (int*)alloc((size_t)NB * 4);
  int2*  packed = (int2*)alloc((size_t)NNZ * 8);          // 12.8 MB
  (void)ws_size; (void)in_sizes; (void)n_in; (void)out_size;

  hipMemsetAsync(gcount, 0, (size_t)NB * 4, stream);

  w1_gemm_kernel<<<(N * E / 2 + 255) / 256, 256, 0, stream>>>(comps1, bases1, W1);
  count_kernel<<<NBLK, 256, 0, stream>>>(hor_rows, gcount);
  scan_kernel<<<1, 1024, 0, stream>>>(gcount, gstart, gcursor);
  scatter_kernel<<<NBLK, 256, 0, stream>>>(hor_rows, hor_cols, values, gcursor,
                                           packed);
  w2_gemm_kernel<<<(R * E * C + 255) / 256, 256, 0, stream>>>(comps2, bases2, W2g);
  layer1_kernel<<<NB, 256, 0, stream>>>(W1, gstart, packed, bias1, h);
  layer2_kernel<<<NB, 256, 0, stream>>>(h, W2g, gstart, packed, bias2, out);
}

// Round 3
// 567.677 us; speedup vs baseline: 1.2647x; 1.0957x over previous
//
#include <hip/hip_runtime.h>
#include <hip/hip_bf16.h>

// Problem constants (match reference)
constexpr int N   = 50000;
constexpr int R   = 51;
constexpr int E   = 16;
constexpr int C   = 8;
constexpr int B   = 40;
constexpr int NNZ = 1600000;

// Bucketed counting sort: 64 nodes/bucket -> LDS-resident accumulators
constexpr int BSH  = 6;
constexpr int BKN  = 1 << BSH;               // 64
constexpr int NB   = (N + BKN - 1) >> BSH;   // 782
constexpr int NPAD = NB * BKN;               // 50048 (padded node count)
constexpr int KS   = 4;                      // k-split factor for layer kernels

// count pass: many small chunks (read-only)
constexpr int CBLK   = 784;
constexpr int CCHUNK = (NNZ + CBLK - 1) / CBLK;   // 2041
// scatter pass: fewer, larger chunks -> ~8-edge (64B) runs per bucket
constexpr int SBLK   = 256;
constexpr int SCHUNK = (NNZ + SBLK - 1) / SBLK;   // 6250

// ---------------------------------------------------------------------------
// K1: W1 = comps1(R,B) @ bases1(B,N*E), output bf16-packed (R, N*E/2) uints.
//     Row (p*N+o) = 8 uints = 32B contiguous -> 2 dwordx4 per gather.
// ---------------------------------------------------------------------------
__global__ __launch_bounds__(256) void w1_gemm_kernel(
    const float* __restrict__ comps1, const float* __restrict__ bases1,
    unsigned* __restrict__ W1u) {
  constexpr int NC2 = N * E / 2;  // 400000 pair-columns
  int j = blockIdx.x * 256 + threadIdx.x;
  if (j >= NC2) return;
  const float2* b2 = reinterpret_cast<const float2*>(bases1);
  float2 col[B];
#pragma unroll
  for (int b = 0; b < B; ++b) col[b] = b2[b * NC2 + j];
#pragma unroll 1
  for (int r = 0; r < R; ++r) {
    float ax = 0.f, ay = 0.f;
#pragma unroll
    for (int b = 0; b < B; ++b) {
      float cc = comps1[r * B + b];   // block-uniform -> scalar loads
      ax = fmaf(cc, col[b].x, ax);
      ay = fmaf(cc, col[b].y, ay);
    }
    unsigned lo = __bfloat16_as_ushort(__float2bfloat16(ax));
    unsigned hi = __bfloat16_as_ushort(__float2bfloat16(ay));
    W1u[r * NC2 + j] = (hi << 16) | lo;
  }
}

// ---------------------------------------------------------------------------
// K2: bucket histogram (LDS-aggregated)
// ---------------------------------------------------------------------------
__global__ __launch_bounds__(256) void count_kernel(
    const int* __restrict__ rows, int* __restrict__ gcount) {
  __shared__ int hist[NB];
  for (int i = threadIdx.x; i < NB; i += 256) hist[i] = 0;
  __syncthreads();
  int lo = blockIdx.x * CCHUNK;
  int hi = lo + CCHUNK < NNZ ? lo + CCHUNK : NNZ;
  for (int i = lo + threadIdx.x; i < hi; i += 256)
    atomicAdd(&hist[rows[i] >> BSH], 1);
  __syncthreads();
  for (int i = threadIdx.x; i < NB; i += 256)
    if (hist[i]) atomicAdd(&gcount[i], hist[i]);
}

// ---------------------------------------------------------------------------
// K3: scan of NB bucket counts -> gstart[NB+1], gcursor[NB]
// ---------------------------------------------------------------------------
__global__ __launch_bounds__(1024) void scan_kernel(
    const int* __restrict__ gcount, int* __restrict__ gstart,
    int* __restrict__ gcursor) {
  __shared__ int buf[1024];
  int t = threadIdx.x;
  int own = (t < NB) ? gcount[t] : 0;
  buf[t] = own;
  __syncthreads();
  for (int d = 1; d < 1024; d <<= 1) {
    int v = (t >= d) ? buf[t - d] : 0;
    __syncthreads();
    buf[t] += v;
    __syncthreads();
  }
  if (t < NB) {
    int st = buf[t] - own;
    gstart[t] = st;
    gcursor[t] = st;
  }
  if (t == NB - 1) gstart[NB] = buf[t];
}

// ---------------------------------------------------------------------------
// K4: scatter into bucket-grouped packed records (8B):
//     word0 = (s_lo<<26) | col,  word1 = val bits. ~64B runs per bucket.
// ---------------------------------------------------------------------------
__global__ __launch_bounds__(256) void scatter_kernel(
    const int* __restrict__ rows, const int* __restrict__ cols,
    const float* __restrict__ vals, int* __restrict__ gcursor,
    int2* __restrict__ packed) {
  __shared__ int hist[NB];
  __shared__ int base[NB];
  for (int i = threadIdx.x; i < NB; i += 256) hist[i] = 0;
  __syncthreads();
  int lo = blockIdx.x * SCHUNK;
  int hi = lo + SCHUNK < NNZ ? lo + SCHUNK : NNZ;
  for (int i = lo + threadIdx.x; i < hi; i += 256)
    atomicAdd(&hist[rows[i] >> BSH], 1);
  __syncthreads();
  for (int i = threadIdx.x; i < NB; i += 256) {
    int c = hist[i];
    base[i] = c ? atomicAdd(&gcursor[i], c) : 0;
  }
  __syncthreads();
  for (int i = threadIdx.x; i < NB; i += 256) hist[i] = 0;  // reuse as cursor
  __syncthreads();
  for (int i = lo + threadIdx.x; i < hi; i += 256) {
    int s = rows[i];
    int b = s >> BSH;
    int pos = base[b] + atomicAdd(&hist[b], 1);
    packed[pos] = make_int2(((s & (BKN - 1)) << 26) | cols[i],
                            __float_as_int(vals[i]));
  }
}

// ---------------------------------------------------------------------------
// K5: W2 = comps2 @ bases2  (tiny)
// ---------------------------------------------------------------------------
__global__ void w2_gemm_kernel(const float* __restrict__ comps2,
                               const float* __restrict__ bases2,
                               float* __restrict__ W2g) {
  int i = blockIdx.x * blockDim.x + threadIdx.x;
  if (i >= R * E * C) return;
  int r = i >> 7;
  int ec = i & 127;
  float acc = 0.f;
#pragma unroll
  for (int b = 0; b < B; ++b)
    acc = fmaf(comps2[r * B + b], bases2[b * 128 + ec], acc);
  W2g[i] = acc;
}

// ---------------------------------------------------------------------------
// K6: layer 1, k-split. Block = (bucket, part). bf16 W1 gather (2 dwordx4),
//     fp32 LDS accum (stride 17), flush plain stores to hpart[part].
// ---------------------------------------------------------------------------
__global__ __launch_bounds__(256) void layer1_kernel(
    const unsigned* __restrict__ W1u, const int* __restrict__ gstart,
    const int2* __restrict__ packed, float* __restrict__ hpart) {
  __shared__ float hacc[BKN * 17];
  for (int i = threadIdx.x; i < BKN * 17; i += 256) hacc[i] = 0.f;
  __syncthreads();
  int bkt = blockIdx.x >> 2, part = blockIdx.x & (KS - 1);
  int lo = gstart[bkt], len = gstart[bkt + 1] - lo;
  int a = lo + ((len * part) >> 2), b = lo + ((len * (part + 1)) >> 2);
  const uint4* W14 = reinterpret_cast<const uint4*>(W1u);
  for (int e = a + threadIdx.x; e < b; e += 256) {
    int2 pk = packed[e];
    int slo = ((unsigned)pk.x) >> 26;
    int col = pk.x & ((1 << 26) - 1);
    float v = __int_as_float(pk.y);
    uint4 w0 = W14[col * 2 + 0];
    uint4 w1 = W14[col * 2 + 1];
    float* hp = &hacc[slo * 17];
    atomicAdd(hp + 0,  v * __uint_as_float(w0.x << 16));
    atomicAdd(hp + 1,  v * __uint_as_float(w0.x & 0xffff0000u));
    atomicAdd(hp + 2,  v * __uint_as_float(w0.y << 16));
    atomicAdd(hp + 3,  v * __uint_as_float(w0.y & 0xffff0000u));
    atomicAdd(hp + 4,  v * __uint_as_float(w0.z << 16));
    atomicAdd(hp + 5,  v * __uint_as_float(w0.z & 0xffff0000u));
    atomicAdd(hp + 6,  v * __uint_as_float(w0.w << 16));
    atomicAdd(hp + 7,  v * __uint_as_float(w0.w & 0xffff0000u));
    atomicAdd(hp + 8,  v * __uint_as_float(w1.x << 16));
    atomicAdd(hp + 9,  v * __uint_as_float(w1.x & 0xffff0000u));
    atomicAdd(hp + 10, v * __uint_as_float(w1.y << 16));
    atomicAdd(hp + 11, v * __uint_as_float(w1.y & 0xffff0000u));
    atomicAdd(hp + 12, v * __uint_as_float(w1.z << 16));
    atomicAdd(hp + 13, v * __uint_as_float(w1.z & 0xffff0000u));
    atomicAdd(hp + 14, v * __uint_as_float(w1.w << 16));
    atomicAdd(hp + 15, v * __uint_as_float(w1.w & 0xffff0000u));
  }
  __syncthreads();
  float* dst = hpart + (size_t)part * (NPAD * E) + ((size_t)bkt << BSH) * E;
  for (int i = threadIdx.x; i < BKN * E; i += 256) {
    int slo = i >> 4, e = i & 15;
    dst[i] = hacc[slo * 17 + e];
  }
}

// ---------------------------------------------------------------------------
// K7: h = relu(sum_part hpart + bias1)   (float4 over N*E)
// ---------------------------------------------------------------------------
__global__ __launch_bounds__(256) void relu_kernel(
    const float* __restrict__ hpart, const float* __restrict__ bias1,
    float* __restrict__ h) {
  int i = blockIdx.x * 256 + threadIdx.x;
  if (i >= N * E / 4) return;
  constexpr int P4 = NPAD * E / 4;
  const float4* hp = reinterpret_cast<const float4*>(hpart);
  float4 s0 = hp[i], s1 = hp[i + P4], s2 = hp[i + 2 * P4], s3 = hp[i + 3 * P4];
  float4 bb = reinterpret_cast<const float4*>(bias1)[i & 3];
  float4 r;
  r.x = fmaxf(s0.x + s1.x + s2.x + s3.x + bb.x, 0.f);
  r.y = fmaxf(s0.y + s1.y + s2.y + s3.y + bb.y, 0.f);
  r.z = fmaxf(s0.z + s1.z + s2.z + s3.z + bb.z, 0.f);
  r.w = fmaxf(s0.w + s1.w + s2.w + s3.w + bb.w, 0.f);
  reinterpret_cast<float4*>(h)[i] = r;
}

// ---------------------------------------------------------------------------
// K8: layer 2, k-split. h[o] gather (L2-resident), W2 in LDS [p][c][e],
//     LDS out accum (stride 9), flush plain stores to opart[part].
// ---------------------------------------------------------------------------
__global__ __launch_bounds__(256) void layer2_kernel(
    const float* __restrict__ h, const float* __restrict__ W2g,
    const int* __restrict__ gstart, const int2* __restrict__ packed,
    float* __restrict__ opart) {
  __shared__ float w2s[R * 132];
  __shared__ float oacc[BKN * 9];
  for (int i = threadIdx.x; i < R * E * C; i += 256) {
    int p = i >> 7, ec = i & 127;     // W2g layout [p][e][c]
    int e = ec >> 3, c = ec & 7;
    w2s[p * 132 + c * 16 + e] = W2g[i];
  }
  for (int i = threadIdx.x; i < BKN * 9; i += 256) oacc[i] = 0.f;
  __syncthreads();
  int bkt = blockIdx.x >> 2, part = blockIdx.x & (KS - 1);
  int lo = gstart[bkt], len = gstart[bkt + 1] - lo;
  int a = lo + ((len * part) >> 2), b = lo + ((len * (part + 1)) >> 2);
  const float4* H4 = reinterpret_cast<const float4*>(h);
  for (int idx = a + threadIdx.x; idx < b; idx += 256) {
    int2 pk = packed[idx];
    int slo = ((unsigned)pk.x) >> 26;
    int col = pk.x & ((1 << 26) - 1);
    float v = __int_as_float(pk.y);
    int p = (int)((unsigned)col / (unsigned)N);
    int o = col - p * N;
    float4 h0 = H4[o * 4 + 0];
    float4 h1 = H4[o * 4 + 1];
    float4 h2 = H4[o * 4 + 2];
    float4 h3 = H4[o * 4 + 3];
    const float4* wp = reinterpret_cast<const float4*>(&w2s[p * 132]);
#pragma unroll
    for (int c = 0; c < 8; ++c) {
      float4 aq = wp[c * 4 + 0];
      float4 bq = wp[c * 4 + 1];
      float4 cq = wp[c * 4 + 2];
      float4 dq = wp[c * 4 + 3];
      float s = h0.x * aq.x + h0.y * aq.y + h0.z * aq.z + h0.w * aq.w
              + h1.x * bq.x + h1.y * bq.y + h1.z * bq.z + h1.w * bq.w
              + h2.x * cq.x + h2.y * cq.y + h2.z * cq.z + h2.w * cq.w
              + h3.x * dq.x + h3.y * dq.y + h3.z * dq.z + h3.w * dq.w;
      atomicAdd(&oacc[slo * 9 + c], v * s);
    }
  }
  __syncthreads();
  float* dst = opart + (size_t)part * (NPAD * C) + ((size_t)bkt << BSH) * C;
  for (int i = threadIdx.x; i < BKN * C; i += 256) {
    int slo = i >> 3, c = i & 7;
    dst[i] = oacc[slo * 9 + c];
  }
}

// ---------------------------------------------------------------------------
// K9: out = sum_part opart + bias2   (float4 over N*C)
// ---------------------------------------------------------------------------
__global__ __launch_bounds__(256) void out_kernel(
    const float* __restrict__ opart, const float* __restrict__ bias2,
    float* __restrict__ out) {
  int i = blockIdx.x * 256 + threadIdx.x;
  if (i >= N * C / 4) return;
  constexpr int P4 = NPAD * C / 4;
  const float4* op = reinterpret_cast<const float4*>(opart);
  float4 s0 = op[i], s1 = op[i + P4], s2 = op[i + 2 * P4], s3 = op[i + 3 * P4];
  float4 bb = reinterpret_cast<const float4*>(bias2)[i & 1];
  float4 r;
  r.x = s0.x + s1.x + s2.x + s3.x + bb.x;
  r.y = s0.y + s1.y + s2.y + s3.y + bb.y;
  r.z = s0.z + s1.z + s2.z + s3.z + bb.z;
  r.w = s0.w + s1.w + s2.w + s3.w + bb.w;
  reinterpret_cast<float4*>(out)[i] = r;
}

// ---------------------------------------------------------------------------
extern "C" void kernel_launch(void* const* d_in, const int* in_sizes, int n_in,
                              void* d_out, int out_size, void* d_ws, size_t ws_size,
                              hipStream_t stream) {
  const float* values  = (const float*)d_in[0];
  const float* comps1  = (const float*)d_in[1];
  const float* bases1  = (const float*)d_in[2];
  const float* comps2  = (const float*)d_in[3];
  const float* bases2  = (const float*)d_in[4];
  const float* bias1   = (const float*)d_in[5];
  const float* bias2   = (const float*)d_in[6];
  const int* hor_rows  = (const int*)d_in[7];
  const int* hor_cols  = (const int*)d_in[8];
  float* out = (float*)d_out;

  char* ws = (char*)d_ws;
  size_t off = 0;
  auto alloc = [&](size_t bytes) {
    void* p = ws + off;
    off += (bytes + 255) & ~size_t(255);
    return p;
  };
  unsigned* W1u    = (unsigned*)alloc((size_t)R * N * E / 2 * 4);   // 81.6 MB
  float*    h      = (float*)alloc((size_t)N * E * 4);              // 3.2 MB
  float*    W2g    = (float*)alloc((size_t)R * E * C * 4);
  int*      gcount = (int*)alloc((size_t)NB * 4);
  int*      gstart = (int*)alloc((size_t)(NB + 1) * 4);
  int*      gcursor= (int*)alloc((size_t)NB * 4);
  int2*     packed = (int2*)alloc((size_t)NNZ * 8);                 // 12.8 MB
  float*    hpart  = (float*)alloc((size_t)KS * NPAD * E * 4);      // 12.8 MB
  float*    opart  = (float*)alloc((size_t)KS * NPAD * C * 4);      // 6.4 MB
  (void)ws_size; (void)in_sizes; (void)n_in; (void)out_size;

  hipMemsetAsync(gcount, 0, (size_t)NB * 4, stream);

  count_kernel<<<CBLK, 256, 0, stream>>>(hor_rows, gcount);
  scan_kernel<<<1, 1024, 0, stream>>>(gcount, gstart, gcursor);
  scatter_kernel<<<SBLK, 256, 0, stream>>>(hor_rows, hor_cols, values, gcursor,
                                           packed);
  w2_gemm_kernel<<<(R * E * C + 255) / 256, 256, 0, stream>>>(comps2, bases2, W2g);
  w1_gemm_kernel<<<(N * E / 2 + 255) / 256, 256, 0, stream>>>(comps1, bases1, W1u);
  layer1_kernel<<<NB * KS, 256, 0, stream>>>(W1u, gstart, packed, hpart);
  relu_kernel<<<(N * E / 4 + 255) / 256, 256, 0, stream>>>(hpart, bias1, h);
  layer2_kernel<<<NB * KS, 256, 0, stream>>>(h, W2g, gstart, packed, opart);
  out_kernel<<<(N * C / 4 + 255) / 256, 256, 0, stream>>>(opart, bias2, out);
}